// Round 4
// baseline (1219.008 us; speedup 1.0000x reference)
//
#include <hip/hip_runtime.h>

// LoRA forward: out[m,o] = sum_d x[m,d]*W[o,d] + b[o] + SCALE * sum_r (sum_d x[m,d]*lora_b[d,r]) * lora_a[r,o]
// M=16384, N=D=4096, K=D=4096, R=8, SCALE=2.0
// Strategy: cast x,W -> bf16 in ws; ts[m,r]=SCALE*x@lora_b fused into x-cast; MFMA bf16 GEMM
// (m97-style 128x128 tile, BK=64, global_load_lds w16, XOR swizzle) with bias+LoRA epilogue.

#define GM 16384
#define GN 4096
#define GK 4096
#define SCALE_C 2.0f

typedef __attribute__((ext_vector_type(8))) short short8;
typedef __attribute__((ext_vector_type(8))) unsigned short ushort8;
typedef __attribute__((ext_vector_type(4))) float float4_;

typedef const __attribute__((address_space(1))) void gvoid;
typedef __attribute__((address_space(3))) void svoid;

__device__ __forceinline__ void gload16(const void* g, void* s) {
    __builtin_amdgcn_global_load_lds((gvoid*)g, (svoid*)s, 16, 0, 0);
}

__device__ __forceinline__ unsigned short f2bf(float f) {
    union { float f; unsigned u; } v; v.f = f;
    unsigned r = v.u + 0x7FFFu + ((v.u >> 16) & 1u);   // RNE (normals; inputs are finite)
    return (unsigned short)(r >> 16);
}

// ---- kernel 1: cast x -> bf16, and ts[m,r] = SCALE * sum_d x[m,d]*lora_b[d,r] ----
// one block per row m (16384 blocks x 256 threads, 16 elems/thread)
__global__ void cast_x_ts(const float* __restrict__ x, const float* __restrict__ lora_b,
                          unsigned short* __restrict__ Xb, float* __restrict__ ts) {
    const int m = blockIdx.x;
    const int tid = threadIdx.x;
    const size_t rowoff = (size_t)m * GK;
    const int d0 = tid * 16;

    const float4_* xp = (const float4_*)(x + rowoff + d0);
    float4_ xv[4];
#pragma unroll
    for (int u = 0; u < 4; ++u) xv[u] = xp[u];

    ushort8 h0, h1;
#pragma unroll
    for (int u = 0; u < 8; ++u) h0[u] = f2bf(xv[u / 4][u % 4]);
#pragma unroll
    for (int u = 0; u < 8; ++u) h1[u] = f2bf(xv[2 + u / 4][u % 4]);
    *(ushort8*)(Xb + rowoff + d0) = h0;
    *(ushort8*)(Xb + rowoff + d0 + 8) = h1;

    float t[8] = {0.f,0.f,0.f,0.f,0.f,0.f,0.f,0.f};
#pragma unroll
    for (int u = 0; u < 16; ++u) {
        float xf = xv[u / 4][u % 4];
        const float4_* lb = (const float4_*)(lora_b + (size_t)(d0 + u) * 8);
        float4_ b0 = lb[0], b1 = lb[1];
#pragma unroll
        for (int r = 0; r < 4; ++r) { t[r] += xf * b0[r]; t[4 + r] += xf * b1[r]; }
    }
    // wave64 reduce
#pragma unroll
    for (int off = 32; off >= 1; off >>= 1) {
#pragma unroll
        for (int r = 0; r < 8; ++r) t[r] += __shfl_down(t[r], off, 64);
    }
    __shared__ float red[4][8];
    const int lane = tid & 63, wave = tid >> 6;
    if (lane == 0) {
#pragma unroll
        for (int r = 0; r < 8; ++r) red[wave][r] = t[r];
    }
    __syncthreads();
    if (tid < 8) {
        float s = red[0][tid] + red[1][tid] + red[2][tid] + red[3][tid];
        ts[(size_t)m * 8 + tid] = s * SCALE_C;
    }
}

// ---- kernel 2: cast W -> bf16 (elementwise) ----
__global__ void cast_w(const float* __restrict__ W, unsigned short* __restrict__ Wb) {
    const size_t i = ((size_t)blockIdx.x * 256 + threadIdx.x) * 8;
    const float4_* p = (const float4_*)(W + i);
    float4_ a = p[0], b = p[1];
    ushort8 h;
#pragma unroll
    for (int r = 0; r < 4; ++r) { h[r] = f2bf(a[r]); h[4 + r] = f2bf(b[r]); }
    *(ushort8*)(Wb + i) = h;
}

// ---- kernel 3: bf16 GEMM (B^T layout) + bias + LoRA epilogue ----
// 128x128 tile, BK=64, 4 waves 2x2 (64x64 each, 4x4 frags of 16x16x32),
// LDS linear dest + inverse-swizzled global source + swizzled ds_read (rule #21).
__global__ void gemm_bt(const unsigned short* __restrict__ A, const unsigned short* __restrict__ B,
                        const float* __restrict__ bias, const float* __restrict__ ts,
                        const float* __restrict__ la, float* __restrict__ out) {
    __shared__ unsigned short lA[128 * 64];
    __shared__ unsigned short lB[128 * 64];

    const int tid = threadIdx.x;
    const int lane = tid & 63;
    const int wave = tid >> 6;
    const int wr = wave >> 1, wc = wave & 1;
    const int m0 = blockIdx.y * 128;
    const int n0 = blockIdx.x * 128;

    float4_ acc[4][4] = {};

    // staging decomposition: thread -> (row-of-32-group, 16B column chunk)
    const int r8 = tid >> 3;           // 0..31
    const int c16 = (tid & 7) << 4;    // byte col within 128B row: 0,16,...,112

    const char* gA = (const char*)(A + (size_t)m0 * GK);
    const char* gB = (const char*)(B + (size_t)n0 * GK);
    char* sA = (char*)lA;
    char* sB = (char*)lB;

    for (int kt = 0; kt < GK; kt += 64) {
#pragma unroll
        for (int g = 0; g < 4; ++g) {
            const int row = g * 32 + r8;
            const int gc = c16 ^ ((row & 7) << 4);   // inverse-swizzled source column
            gload16(gA + (size_t)row * (GK * 2) + (size_t)kt * 2 + gc, sA + row * 128 + c16);
            gload16(gB + (size_t)row * (GK * 2) + (size_t)kt * 2 + gc, sB + row * 128 + c16);
        }
        __syncthreads();   // drains vmcnt -> staged data visible

#pragma unroll
        for (int kk = 0; kk < 64; kk += 32) {
            const int colb = (kk + (lane >> 4) * 8) * 2;   // byte col of this lane's 8 bf16
            short8 av[4], bv[4];
#pragma unroll
            for (int i = 0; i < 4; ++i) {
                const int row = wr * 64 + i * 16 + (lane & 15);
                av[i] = *(const short8*)(sA + row * 128 + (colb ^ ((row & 7) << 4)));
            }
#pragma unroll
            for (int j = 0; j < 4; ++j) {
                const int row = wc * 64 + j * 16 + (lane & 15);
                bv[j] = *(const short8*)(sB + row * 128 + (colb ^ ((row & 7) << 4)));
            }
#pragma unroll
            for (int i = 0; i < 4; ++i)
#pragma unroll
                for (int j = 0; j < 4; ++j)
                    acc[i][j] = __builtin_amdgcn_mfma_f32_16x16x32_bf16(av[i], bv[j], acc[i][j], 0, 0, 0);
        }
        __syncthreads();   // all reads done before next stage overwrites
    }

    // epilogue: C/D layout col=lane&15, row=(lane>>4)*4+reg  [m89]
    const int lrow = lane & 15, kgrp = lane >> 4;
    float areg[4][8];
    float bj[4];
    int ocol[4];
#pragma unroll
    for (int j = 0; j < 4; ++j) {
        const int o = n0 + wc * 64 + j * 16 + lrow;
        ocol[j] = o;
        bj[j] = bias[o];
#pragma unroll
        for (int r = 0; r < 8; ++r) areg[j][r] = la[(size_t)r * GN + o];
    }
#pragma unroll
    for (int i = 0; i < 4; ++i) {
#pragma unroll
        for (int reg = 0; reg < 4; ++reg) {
            const int m = m0 + wr * 64 + i * 16 + kgrp * 4 + reg;
            const float4_* tp = (const float4_*)(ts + (size_t)m * 8);
            const float4_ t0 = tp[0], t1 = tp[1];
            float* orow = out + (size_t)m * GN;
#pragma unroll
            for (int j = 0; j < 4; ++j) {
                const float lor = t0[0]*areg[j][0] + t0[1]*areg[j][1] + t0[2]*areg[j][2] + t0[3]*areg[j][3]
                                + t1[0]*areg[j][4] + t1[1]*areg[j][5] + t1[2]*areg[j][6] + t1[3]*areg[j][7];
                orow[ocol[j]] = acc[i][j][reg] + bj[j] + lor;
            }
        }
    }
}

extern "C" void kernel_launch(void* const* d_in, const int* in_sizes, int n_in,
                              void* d_out, int out_size, void* d_ws, size_t ws_size,
                              hipStream_t stream) {
    const float* x      = (const float*)d_in[0];
    const float* W      = (const float*)d_in[1];
    const float* b      = (const float*)d_in[2];
    const float* lora_a = (const float*)d_in[3];
    const float* lora_b = (const float*)d_in[4];
    float* out = (float*)d_out;

    char* ws = (char*)d_ws;
    unsigned short* Xb = (unsigned short*)ws;                                   // 128 MiB
    unsigned short* Wb = (unsigned short*)(ws + (size_t)134217728);             // 32 MiB
    float*          ts = (float*)(ws + (size_t)134217728 + 33554432);           // 0.5 MiB

    cast_x_ts<<<GM, 256, 0, stream>>>(x, lora_b, Xb, ts);
    cast_w<<<GN * GK / (256 * 8), 256, 0, stream>>>(W, Wb);
    gemm_bt<<<dim3(GN / 128, GM / 128), 256, 0, stream>>>(Xb, Wb, b, ts, lora_a, out);
}

// Round 5
// 1177.767 us; speedup vs baseline: 1.0350x; 1.0350x over previous
//
#include <hip/hip_runtime.h>

// LoRA forward: out[m,o] = sum_d x[m,d]*W[o,d] + b[o] + SCALE * ts[m,:]@lora_a[:,o]
// M=16384, N=D=4096, K=D=4096, R=8, SCALE=2.0
// R4 baseline: 2-barrier 128^2 GEMM = 526us @1050TF, MfmaUtil 49.5%, conflicts 0.
// R5: 256^2 8-phase counted-vmcnt GEMM (T2+T3+T4+T5), zero-conflict XOR swizzle kept.

#define GM 16384
#define GN 4096
#define GK 4096
#define NT (GK / 64)
#define SCALE_C 2.0f

typedef __attribute__((ext_vector_type(8))) short short8;
typedef __attribute__((ext_vector_type(8))) unsigned short ushort8;
typedef __attribute__((ext_vector_type(4))) float float4_;

typedef const __attribute__((address_space(1))) void gvoid;
typedef __attribute__((address_space(3))) void svoid;

__device__ __forceinline__ void gload16(const void* g, void* s) {
    __builtin_amdgcn_global_load_lds((gvoid*)g, (svoid*)s, 16, 0, 0);
}

__device__ __forceinline__ unsigned short f2bf(float f) {
    union { float f; unsigned u; } v; v.f = f;
    unsigned r = v.u + 0x7FFFu + ((v.u >> 16) & 1u);
    return (unsigned short)(r >> 16);
}

// ---- kernel 1: cast x -> bf16 + ts[m,r] = SCALE * x[m,:]@lora_b[:,r] (unchanged from r4) ----
__global__ void cast_x_ts(const float* __restrict__ x, const float* __restrict__ lora_b,
                          unsigned short* __restrict__ Xb, float* __restrict__ ts) {
    const int m = blockIdx.x;
    const int tid = threadIdx.x;
    const size_t rowoff = (size_t)m * GK;
    const int d0 = tid * 16;

    const float4_* xp = (const float4_*)(x + rowoff + d0);
    float4_ xv[4];
#pragma unroll
    for (int u = 0; u < 4; ++u) xv[u] = xp[u];

    ushort8 h0, h1;
#pragma unroll
    for (int u = 0; u < 8; ++u) h0[u] = f2bf(xv[u / 4][u % 4]);
#pragma unroll
    for (int u = 0; u < 8; ++u) h1[u] = f2bf(xv[2 + u / 4][u % 4]);
    *(ushort8*)(Xb + rowoff + d0) = h0;
    *(ushort8*)(Xb + rowoff + d0 + 8) = h1;

    float t[8] = {0.f,0.f,0.f,0.f,0.f,0.f,0.f,0.f};
#pragma unroll
    for (int u = 0; u < 16; ++u) {
        float xf = xv[u / 4][u % 4];
        const float4_* lb = (const float4_*)(lora_b + (size_t)(d0 + u) * 8);
        float4_ b0 = lb[0], b1 = lb[1];
#pragma unroll
        for (int r = 0; r < 4; ++r) { t[r] += xf * b0[r]; t[4 + r] += xf * b1[r]; }
    }
#pragma unroll
    for (int off = 32; off >= 1; off >>= 1) {
#pragma unroll
        for (int r = 0; r < 8; ++r) t[r] += __shfl_down(t[r], off, 64);
    }
    __shared__ float red[4][8];
    const int lane = tid & 63, wave = tid >> 6;
    if (lane == 0) {
#pragma unroll
        for (int r = 0; r < 8; ++r) red[wave][r] = t[r];
    }
    __syncthreads();
    if (tid < 8) {
        float s = red[0][tid] + red[1][tid] + red[2][tid] + red[3][tid];
        ts[(size_t)m * 8 + tid] = s * SCALE_C;
    }
}

// ---- kernel 2: cast W -> bf16 (unchanged) ----
__global__ void cast_w(const float* __restrict__ W, unsigned short* __restrict__ Wb) {
    const size_t i = ((size_t)blockIdx.x * 256 + threadIdx.x) * 8;
    const float4_* p = (const float4_*)(W + i);
    float4_ a = p[0], b = p[1];
    ushort8 h;
#pragma unroll
    for (int r = 0; r < 4; ++r) { h[r] = f2bf(a[r]); h[4 + r] = f2bf(b[r]); }
    *(ushort8*)(Wb + i) = h;
}

// ---- kernel 3: 256x256-tile 8-phase bf16 GEMM + bias + LoRA epilogue ----
// 512 thr = 8 waves (2M x 4N), per-wave 128x64 out, BK=64, LDS 128KiB dbuf.
// Phases/K-tile: ph1{rd A-lo,B-lo | stage A-lo(t+1)} ph2{rd B-hi | stage A-hi(t+1)}
// ph3{rd A-hi | stage B-lo(t+2)} ph4{stage B-hi(t+2), vmcnt(4)}; each phase:
// barrier -> setprio(1) -> 16 MFMA -> setprio(0) -> barrier. vmcnt never 0 in main loop.

#define BARRIER __builtin_amdgcn_s_barrier()
#define PRIO1 __builtin_amdgcn_s_setprio(1)
#define PRIO0 __builtin_amdgcn_s_setprio(0)

#define MM8(AH, BH, FO, JO)                                                    \
    _Pragma("unroll") for (int kk = 0; kk < 2; ++kk)                           \
    _Pragma("unroll") for (int f = 0; f < 4; ++f)                              \
    _Pragma("unroll") for (int j = 0; j < 2; ++j)                              \
        acc[(FO) + f][(JO) + j] = __builtin_amdgcn_mfma_f32_16x16x32_bf16(     \
            AH[f][kk], BH[j][kk], acc[(FO) + f][(JO) + j], 0, 0, 0)

// stage one half-tile (128 rows x 128B): 2 x gload16 per thread (8 waves cover it)
#define STAGE(G, LB, KT, H)                                                    \
    do {                                                                       \
        _Pragma("unroll") for (int l = 0; l < 2; ++l)                          \
            gload16((G) + (size_t)((H) * 128 + wave * 16 + l * 8 + ln8) * (GK * 2) \
                        + (size_t)(KT) * 128 + sgc,                            \
                    ldsc + (LB) + (H) * 16384 + (wave * 128 + l * 64 + lane) * 16); \
    } while (0)

#define KTILE_BODY(T, SA, SB, VMC)                                             \
    do {                                                                       \
        const int b_ = (T) & 1;                                                \
        const int Ab_ = b_ * 65536, Bb_ = Ab_ + 32768;                         \
        const int An_ = (1 - b_) * 65536;                                      \
        short8 al[4][2], ah[4][2], bl[2][2], bh[2][2];                         \
        /* ph1 */                                                              \
        _Pragma("unroll") for (int f = 0; f < 4; ++f)                          \
        _Pragma("unroll") for (int kk = 0; kk < 2; ++kk)                       \
            al[f][kk] = *(const short8*)(ldsc + Ab_ + (wm * 128 + f * 16 + l15) * 128 + cofs[kk]); \
        _Pragma("unroll") for (int j = 0; j < 2; ++j)                          \
        _Pragma("unroll") for (int kk = 0; kk < 2; ++kk)                       \
            bl[j][kk] = *(const short8*)(ldsc + Bb_ + (wn * 64 + j * 16 + l15) * 128 + cofs[kk]); \
        if (SA) STAGE(gA, An_, (T) + 1, 0);                                    \
        BARRIER;                                                               \
        PRIO1; MM8(al, bl, 0, 0); PRIO0;                                       \
        BARRIER;                                                               \
        /* ph2 */                                                              \
        _Pragma("unroll") for (int j = 0; j < 2; ++j)                          \
        _Pragma("unroll") for (int kk = 0; kk < 2; ++kk)                       \
            bh[j][kk] = *(const short8*)(ldsc + Bb_ + (wn * 64 + (2 + j) * 16 + l15) * 128 + cofs[kk]); \
        if (SA) STAGE(gA, An_, (T) + 1, 1);                                    \
        BARRIER;                                                               \
        PRIO1; MM8(al, bh, 0, 2); PRIO0;                                       \
        BARRIER;                                                               \
        /* ph3 */                                                              \
        _Pragma("unroll") for (int f = 0; f < 4; ++f)                          \
        _Pragma("unroll") for (int kk = 0; kk < 2; ++kk)                       \
            ah[f][kk] = *(const short8*)(ldsc + Ab_ + (wm * 128 + (4 + f) * 16 + l15) * 128 + cofs[kk]); \
        if (SB) STAGE(gB, Bb_, (T) + 2, 0);                                    \
        BARRIER;                                                               \
        PRIO1; MM8(ah, bh, 4, 2); PRIO0;                                       \
        BARRIER;                                                               \
        /* ph4 */                                                              \
        if (SB) STAGE(gB, Bb_, (T) + 2, 1);                                    \
        if ((VMC) == 4) asm volatile("s_waitcnt vmcnt(4)" ::: "memory");       \
        if ((VMC) == 0) asm volatile("s_waitcnt vmcnt(0)" ::: "memory");       \
        BARRIER;                                                               \
        PRIO1; MM8(ah, bl, 4, 0); PRIO0;                                       \
        BARRIER;                                                               \
    } while (0)

__global__ __launch_bounds__(512, 2) void gemm8p(
        const unsigned short* __restrict__ A, const unsigned short* __restrict__ B,
        const float* __restrict__ bias, const float* __restrict__ ts,
        const float* __restrict__ la, float* __restrict__ out) {
    __shared__ char ldsbuf[131072];   // buf b: A at b*64K, B at b*64K+32K
    char* ldsc = ldsbuf;

    const int tid = threadIdx.x;
    const int lane = tid & 63;
    const int wave = tid >> 6;       // 0..7
    const int wm = wave >> 2;        // 0..1  (M half: 128 rows)
    const int wn = wave & 3;         // 0..3  (N quarter: 64 cols)
    const int l15 = lane & 15;
    const int ln8 = lane >> 3;

    // XCD-bijective swizzle: 1024 wgs, 1024%8==0
    int wg = (int)blockIdx.x;
    wg = (wg & 7) * 128 + (wg >> 3);
    const int tm = wg >> 4, tn = wg & 15;
    const size_t m0 = (size_t)tm * 256, n0 = (size_t)tn * 256;

    const char* gA = (const char*)(A + m0 * GK);
    const char* gB = (const char*)(B + n0 * GK);

    // staging source swizzle (inverse of read swizzle; row&7 == lane>>3)
    const int sgc = ((lane & 7) << 4) ^ (ln8 << 4);
    // ds_read column offsets per k-slice (lane-const): (kk*64 + (lane>>4)*16) ^ ((lane&7)<<4)
    int cofs[2];
#pragma unroll
    for (int kk = 0; kk < 2; ++kk)
        cofs[kk] = (kk * 64 + ((lane >> 4) << 4)) ^ ((lane & 7) << 4);

    float4_ acc[8][4] = {};

    // prologue: stage A(0) both halves, B(0) both, B(1) both; drain to 4 (B(1) in flight)
    STAGE(gA, 0, 0, 0);
    STAGE(gA, 0, 0, 1);
    STAGE(gB, 32768, 0, 0);
    STAGE(gB, 32768, 0, 1);
    STAGE(gB, 65536 + 32768, 1, 0);
    STAGE(gB, 65536 + 32768, 1, 1);
    asm volatile("s_waitcnt vmcnt(4)" ::: "memory");
    BARRIER;

    for (int t = 0; t < NT - 2; ++t) {
        KTILE_BODY(t, 1, 1, 4);
    }
    KTILE_BODY(NT - 2, 1, 0, 0);
    KTILE_BODY(NT - 1, 0, 0, -1);

    // epilogue: C/D frag layout col=lane&15, row=(lane>>4)*4+reg  [m89]
    const int kg = lane >> 4;
    float bj[4], areg[4][8];
    int ocol[4];
#pragma unroll
    for (int j = 0; j < 4; ++j) {
        const int o = (int)n0 + wn * 64 + j * 16 + l15;
        ocol[j] = o;
        bj[j] = bias[o];
#pragma unroll
        for (int r = 0; r < 8; ++r) areg[j][r] = la[(size_t)r * GN + o];
    }
#pragma unroll
    for (int f = 0; f < 8; ++f) {
#pragma unroll
        for (int reg = 0; reg < 4; ++reg) {
            const size_t m = m0 + wm * 128 + f * 16 + kg * 4 + reg;
            const float4_* tp = (const float4_*)(ts + m * 8);
            const float4_ t0 = tp[0], t1 = tp[1];
            float* orow = out + m * GN;
#pragma unroll
            for (int j = 0; j < 4; ++j) {
                const float lor = t0[0]*areg[j][0] + t0[1]*areg[j][1] + t0[2]*areg[j][2] + t0[3]*areg[j][3]
                                + t1[0]*areg[j][4] + t1[1]*areg[j][5] + t1[2]*areg[j][6] + t1[3]*areg[j][7];
                orow[ocol[j]] = acc[f][j][reg] + bj[j] + lor;
            }
        }
    }
}

extern "C" void kernel_launch(void* const* d_in, const int* in_sizes, int n_in,
                              void* d_out, int out_size, void* d_ws, size_t ws_size,
                              hipStream_t stream) {
    const float* x      = (const float*)d_in[0];
    const float* W      = (const float*)d_in[1];
    const float* b      = (const float*)d_in[2];
    const float* lora_a = (const float*)d_in[3];
    const float* lora_b = (const float*)d_in[4];
    float* out = (float*)d_out;

    char* ws = (char*)d_ws;
    unsigned short* Xb = (unsigned short*)ws;
    unsigned short* Wb = (unsigned short*)(ws + (size_t)134217728);
    float*          ts = (float*)(ws + (size_t)134217728 + 33554432);

    cast_x_ts<<<GM, 256, 0, stream>>>(x, lora_b, Xb, ts);
    cast_w<<<GN * GK / (256 * 8), 256, 0, stream>>>(W, Wb);
    gemm8p<<<(GM / 256) * (GN / 256), 512, 0, stream>>>(Xb, Wb, b, ts, lora_a, out);
}

// Round 8
// 1175.610 us; speedup vs baseline: 1.0369x; 1.0018x over previous
//
#include <hip/hip_runtime.h>

// LoRA forward: out[m,o] = sum_d x[m,d]*W[o,d] + b[o] + SCALE * ts[m,:]@lora_a[:,o]
// M=16384, N=D=4096, K=D=4096, R=8, SCALE=2.0
// R4: 2-phase 128^2 = 526us @1050TF. R5: 8-phase 256^2 = 518us @48.7% (PASS, absmax 0.03125).
// R6: + sched pins -> BROKE correctness (absmax 7.28 = GEMM contribution missing; m152 race).
// R7: GEMM reverted to R5-verified exactly. cast_x_ts rewritten one-wave-per-row to probe
// the ~660us of non-gemm time.

#define GM 16384
#define GN 4096
#define GK 4096
#define NT (GK / 64)
#define SCALE_C 2.0f

typedef __attribute__((ext_vector_type(8))) short short8;
typedef __attribute__((ext_vector_type(8))) unsigned short ushort8;
typedef __attribute__((ext_vector_type(4))) float float4_;

typedef const __attribute__((address_space(1))) void gvoid;
typedef __attribute__((address_space(3))) void svoid;

__device__ __forceinline__ void gload16(const void* g, void* s) {
    __builtin_amdgcn_global_load_lds((gvoid*)g, (svoid*)s, 16, 0, 0);
}

__device__ __forceinline__ unsigned short f2bf(float f) {
    union { float f; unsigned u; } v; v.f = f;
    unsigned r = v.u + 0x7FFFu + ((v.u >> 16) & 1u);
    return (unsigned short)(r >> 16);
}

// ---- kernel 1: cast x -> bf16 + ts[m,r] = SCALE * x[m,:]@lora_b[:,r] ----
// R7: one wave per row; lane owns 64 contiguous d's; xor-butterfly reduce (no LDS).
__global__ void cast_x_ts(const float* __restrict__ x, const float* __restrict__ lora_b,
                          unsigned short* __restrict__ Xb, float* __restrict__ ts) {
    const int l = threadIdx.x & 63;
    const int w = threadIdx.x >> 6;
    const int m = blockIdx.x * 4 + w;          // grid 4096 x 256thr = 4 rows/block
    const size_t ro = (size_t)m * GK;
    const float* xr = x + ro + l * 64;
    const float* lb = lora_b + (size_t)l * 64 * 8;

    float t[8] = {0.f,0.f,0.f,0.f,0.f,0.f,0.f,0.f};
#pragma unroll
    for (int u2 = 0; u2 < 8; ++u2) {
        const float4_ xa = ((const float4_*)xr)[2 * u2];
        const float4_ xb = ((const float4_*)xr)[2 * u2 + 1];
        ushort8 h;
#pragma unroll
        for (int e = 0; e < 4; ++e) { h[e] = f2bf(xa[e]); h[4 + e] = f2bf(xb[e]); }
        *(ushort8*)(Xb + ro + l * 64 + u2 * 8) = h;
#pragma unroll
        for (int e = 0; e < 8; ++e) {
            const float xv = (e < 4) ? xa[e] : xb[e - 4];
            const int d = u2 * 8 + e;
            const float4_ b0 = ((const float4_*)(lb + d * 8))[0];
            const float4_ b1 = ((const float4_*)(lb + d * 8))[1];
#pragma unroll
            for (int r = 0; r < 4; ++r) { t[r] += xv * b0[r]; t[4 + r] += xv * b1[r]; }
        }
    }
#pragma unroll
    for (int mk = 32; mk >= 1; mk >>= 1) {
#pragma unroll
        for (int r = 0; r < 8; ++r) t[r] += __shfl_xor(t[r], mk, 64);
    }
    if (l < 8) ts[(size_t)m * 8 + l] = t[l] * SCALE_C;
}

// ---- kernel 2: cast W -> bf16 (unchanged, verified) ----
__global__ void cast_w(const float* __restrict__ W, unsigned short* __restrict__ Wb) {
    const size_t i = ((size_t)blockIdx.x * 256 + threadIdx.x) * 8;
    const float4_* p = (const float4_*)(W + i);
    float4_ a = p[0], b = p[1];
    ushort8 h;
#pragma unroll
    for (int r = 0; r < 4; ++r) { h[r] = f2bf(a[r]); h[4 + r] = f2bf(b[r]); }
    *(ushort8*)(Wb + i) = h;
}

// ---- kernel 3: 256x256-tile 8-phase bf16 GEMM + bias + LoRA epilogue ----
// EXACT R5-verified source (PASS @518us). No sched pins (R6's pins raced — m152).
// 512 thr = 8 waves (2M x 4N), per-wave 128x64 out, BK=64, LDS 128KiB dbuf.

#define BARRIER __builtin_amdgcn_s_barrier()
#define PRIO1 __builtin_amdgcn_s_setprio(1)
#define PRIO0 __builtin_amdgcn_s_setprio(0)

#define MM8(AH, BH, FO, JO)                                                    \
    _Pragma("unroll") for (int kk = 0; kk < 2; ++kk)                           \
    _Pragma("unroll") for (int f = 0; f < 4; ++f)                              \
    _Pragma("unroll") for (int j = 0; j < 2; ++j)                              \
        acc[(FO) + f][(JO) + j] = __builtin_amdgcn_mfma_f32_16x16x32_bf16(     \
            AH[f][kk], BH[j][kk], acc[(FO) + f][(JO) + j], 0, 0, 0)

#define STAGE(G, LB, KT, H)                                                    \
    do {                                                                       \
        _Pragma("unroll") for (int l = 0; l < 2; ++l)                          \
            gload16((G) + (size_t)((H) * 128 + wave * 16 + l * 8 + ln8) * (GK * 2) \
                        + (size_t)(KT) * 128 + sgc,                            \
                    ldsc + (LB) + (H) * 16384 + (wave * 128 + l * 64 + lane) * 16); \
    } while (0)

#define KTILE_BODY(T, SA, SB, VMC)                                             \
    do {                                                                       \
        const int b_ = (T) & 1;                                                \
        const int Ab_ = b_ * 65536, Bb_ = Ab_ + 32768;                         \
        const int An_ = (1 - b_) * 65536;                                      \
        short8 al[4][2], ah[4][2], bl[2][2], bh[2][2];                         \
        /* ph1 */                                                              \
        _Pragma("unroll") for (int f = 0; f < 4; ++f)                          \
        _Pragma("unroll") for (int kk = 0; kk < 2; ++kk)                       \
            al[f][kk] = *(const short8*)(ldsc + Ab_ + (wm * 128 + f * 16 + l15) * 128 + cofs[kk]); \
        _Pragma("unroll") for (int j = 0; j < 2; ++j)                          \
        _Pragma("unroll") for (int kk = 0; kk < 2; ++kk)                       \
            bl[j][kk] = *(const short8*)(ldsc + Bb_ + (wn * 64 + j * 16 + l15) * 128 + cofs[kk]); \
        if (SA) STAGE(gA, An_, (T) + 1, 0);                                    \
        BARRIER;                                                               \
        PRIO1; MM8(al, bl, 0, 0); PRIO0;                                       \
        BARRIER;                                                               \
        /* ph2 */                                                              \
        _Pragma("unroll") for (int j = 0; j < 2; ++j)                          \
        _Pragma("unroll") for (int kk = 0; kk < 2; ++kk)                       \
            bh[j][kk] = *(const short8*)(ldsc + Bb_ + (wn * 64 + (2 + j) * 16 + l15) * 128 + cofs[kk]); \
        if (SA) STAGE(gA, An_, (T) + 1, 1);                                    \
        BARRIER;                                                               \
        PRIO1; MM8(al, bh, 0, 2); PRIO0;                                       \
        BARRIER;                                                               \
        /* ph3 */                                                              \
        _Pragma("unroll") for (int f = 0; f < 4; ++f)                          \
        _Pragma("unroll") for (int kk = 0; kk < 2; ++kk)                       \
            ah[f][kk] = *(const short8*)(ldsc + Ab_ + (wm * 128 + (4 + f) * 16 + l15) * 128 + cofs[kk]); \
        if (SB) STAGE(gB, Bb_, (T) + 2, 0);                                    \
        BARRIER;                                                               \
        PRIO1; MM8(ah, bh, 4, 2); PRIO0;                                       \
        BARRIER;                                                               \
        /* ph4 */                                                              \
        if (SB) STAGE(gB, Bb_, (T) + 2, 1);                                    \
        if ((VMC) == 4) asm volatile("s_waitcnt vmcnt(4)" ::: "memory");       \
        if ((VMC) == 0) asm volatile("s_waitcnt vmcnt(0)" ::: "memory");       \
        BARRIER;                                                               \
        PRIO1; MM8(ah, bl, 4, 0); PRIO0;                                       \
        BARRIER;                                                               \
    } while (0)

__global__ __launch_bounds__(512, 2) void gemm8p(
        const unsigned short* __restrict__ A, const unsigned short* __restrict__ B,
        const float* __restrict__ bias, const float* __restrict__ ts,
        const float* __restrict__ la, float* __restrict__ out) {
    __shared__ char ldsbuf[131072];
    char* ldsc = ldsbuf;

    const int tid = threadIdx.x;
    const int lane = tid & 63;
    const int wave = tid >> 6;
    const int wm = wave >> 2;
    const int wn = wave & 3;
    const int l15 = lane & 15;
    const int ln8 = lane >> 3;

    int wg = (int)blockIdx.x;
    wg = (wg & 7) * 128 + (wg >> 3);
    const int tm = wg >> 4, tn = wg & 15;
    const size_t m0 = (size_t)tm * 256, n0 = (size_t)tn * 256;

    const char* gA = (const char*)(A + m0 * GK);
    const char* gB = (const char*)(B + n0 * GK);

    const int sgc = ((lane & 7) << 4) ^ (ln8 << 4);
    int cofs[2];
#pragma unroll
    for (int kk = 0; kk < 2; ++kk)
        cofs[kk] = (kk * 64 + ((lane >> 4) << 4)) ^ ((lane & 7) << 4);

    float4_ acc[8][4] = {};

    STAGE(gA, 0, 0, 0);
    STAGE(gA, 0, 0, 1);
    STAGE(gB, 32768, 0, 0);
    STAGE(gB, 32768, 0, 1);
    STAGE(gB, 65536 + 32768, 1, 0);
    STAGE(gB, 65536 + 32768, 1, 1);
    asm volatile("s_waitcnt vmcnt(4)" ::: "memory");
    BARRIER;

    for (int t = 0; t < NT - 2; ++t) {
        KTILE_BODY(t, 1, 1, 4);
    }
    KTILE_BODY(NT - 2, 1, 0, 0);
    KTILE_BODY(NT - 1, 0, 0, -1);

    const int kg = lane >> 4;
    float bj[4], areg[4][8];
    int ocol[4];
#pragma unroll
    for (int j = 0; j < 4; ++j) {
        const int o = (int)n0 + wn * 64 + j * 16 + l15;
        ocol[j] = o;
        bj[j] = bias[o];
#pragma unroll
        for (int r = 0; r < 8; ++r) areg[j][r] = la[(size_t)r * GN + o];
    }
#pragma unroll
    for (int f = 0; f < 8; ++f) {
#pragma unroll
        for (int reg = 0; reg < 4; ++reg) {
            const size_t m = m0 + wm * 128 + f * 16 + kg * 4 + reg;
            const float4_* tp = (const float4_*)(ts + m * 8);
            const float4_ t0 = tp[0], t1 = tp[1];
            float* orow = out + m * GN;
#pragma unroll
            for (int j = 0; j < 4; ++j) {
                const float lor = t0[0]*areg[j][0] + t0[1]*areg[j][1] + t0[2]*areg[j][2] + t0[3]*areg[j][3]
                                + t1[0]*areg[j][4] + t1[1]*areg[j][5] + t1[2]*areg[j][6] + t1[3]*areg[j][7];
                orow[ocol[j]] = acc[f][j][reg] + bj[j] + lor;
            }
        }
    }
}

extern "C" void kernel_launch(void* const* d_in, const int* in_sizes, int n_in,
                              void* d_out, int out_size, void* d_ws, size_t ws_size,
                              hipStream_t stream) {
    const float* x      = (const float*)d_in[0];
    const float* W      = (const float*)d_in[1];
    const float* b      = (const float*)d_in[2];
    const float* lora_a = (const float*)d_in[3];
    const float* lora_b = (const float*)d_in[4];
    float* out = (float*)d_out;

    char* ws = (char*)d_ws;
    unsigned short* Xb = (unsigned short*)ws;
    unsigned short* Wb = (unsigned short*)(ws + (size_t)134217728);
    float*          ts = (float*)(ws + (size_t)134217728 + 33554432);

    cast_x_ts<<<GM / 4, 256, 0, stream>>>(x, lora_b, Xb, ts);
    cast_w<<<GN * GK / (256 * 8), 256, 0, stream>>>(W, Wb);
    gemm8p<<<(GM / 256) * (GN / 256), 512, 0, stream>>>(Xb, Wb, b, ts, lora_a, out);
}